// Round 2
// baseline (11.935 us; speedup 1.0000x reference)
//
#include <hip/hip_runtime.h>

// TT embedding gather, wave-independent form.
// out[t, e] = sum_r left[v/62500, r] * core2[r, (v%62500)*64 + e]
// left[i0*4+i1, r] = sum_b core0[0,i0,b] * core1[b,i1,r]   (wave-uniform: 64 FMAs)
//
// Shapes: ids (16,512) int32, core0 (1,2,8), core1 (8,4,8), core2 (8,4000000,1).
// Output (16,512,64) fp32.
//
// Structure: 1 wave per token, lane = embed dim. No LDS, no barriers —
// each wave's critical path is: s_load id -> 8 independent core2 loads -> 8 FMA.
// The 64 redundant left-row FMAs (wave-uniform) hide under core2 HBM latency.
// 1024-thread blocks -> 512 workgroups, exactly 2 blocks/CU.

#define TT_D1   4
#define TT_D2   4000000
#define TT_RANK 8
#define TT_NTOK (16 * 512)
#define TT_EMB  64
#define TT_VDIV 62500   // TT_D2 / TT_EMB

__global__ __launch_bounds__(1024) void TTEmbeddingLayer_84713934946739_kernel(
    const int*   __restrict__ ids,
    const float* __restrict__ core0,
    const float* __restrict__ core1,
    const float* __restrict__ core2,
    float*       __restrict__ out)
{
    const int lane = threadIdx.x & 63;
    const int wave = threadIdx.x >> 6;               // 0..15
    const int tok  = blockIdx.x * 16 + wave;         // 512*16 == 8192 == NTOK, no tail

    const int v  = ids[tok];                         // wave-uniform -> scalar load
    const int i  = v / TT_VDIV;                      // 0..7
    const int i0 = i >> 2;                           // 0..1
    const int i1 = i & 3;                            // 0..3
    const int base = (v - i * TT_VDIV) * TT_EMB + lane;

    // Issue the 8 core2 row-segment loads immediately (independent of left).
    float x[TT_RANK];
#pragma unroll
    for (int r = 0; r < TT_RANK; ++r)
        x[r] = core2[r * TT_D2 + base];

    // Wave-uniform left row: left[i][r] = sum_b core0[i0*8+b] * core1[(b*4+i1)*8+r].
    // core0/core1 total 1.2 KB -> L2-hot after first block; VALU work hides
    // under the core2 loads above.
    float l[TT_RANK];
#pragma unroll
    for (int r = 0; r < TT_RANK; ++r) l[r] = 0.f;
#pragma unroll
    for (int b = 0; b < TT_RANK; ++b) {
        const float a = core0[i0 * TT_RANK + b];
#pragma unroll
        for (int r = 0; r < TT_RANK; ++r)
            l[r] += a * core1[(b * TT_D1 + i1) * TT_RANK + r];
    }

    float acc = 0.f;
#pragma unroll
    for (int r = 0; r < TT_RANK; ++r)
        acc += l[r] * x[r];

    out[tok * TT_EMB + lane] = acc;
}

extern "C" void kernel_launch(void* const* d_in, const int* in_sizes, int n_in,
                              void* d_out, int out_size, void* d_ws, size_t ws_size,
                              hipStream_t stream) {
    const int*   ids   = (const int*)  d_in[0];
    const float* core0 = (const float*)d_in[1];
    const float* core1 = (const float*)d_in[2];
    const float* core2 = (const float*)d_in[3];
    float*       out   = (float*)      d_out;

    const int blocks = TT_NTOK / 16;  // 16 waves (tokens) per 1024-thread block
    TTEmbeddingLayer_84713934946739_kernel<<<blocks, 1024, 0, stream>>>(
        ids, core0, core1, core2, out);
}

// Round 3
// 9.586 us; speedup vs baseline: 1.2450x; 1.2450x over previous
//
#include <hip/hip_runtime.h>

// TT embedding gather with 4-token-per-wave ILP.
// out[t, e] = sum_r left[v/62500, r] * core2[r, (v%62500)*64 + e]
// left[i0*4+i1, r] = sum_b core0[0,i0,b] * core1[b,i1,r]   (8x8, tiny, in LDS)
//
// ids (16,512) int32, core0 (1,2,8), core1 (8,4,8), core2 (8,4000000,1) fp32.
// Output (16,512,64) fp32.
//
// Structure: wave = 4 tokens, lane = embed dim. Issue all ids loads, then all
// 32 core2 segment loads (independent -> deep MLP), overlap the 8x8 left
// computation (wave 0 only) under those loads, one barrier, then 4 dots.

#define TT_D1   4
#define TT_D2   4000000
#define TT_RANK 8
#define TT_NTOK (16 * 512)
#define TT_EMB  64
#define TT_VDIV 62500       // TT_D2 / TT_EMB
#define T_PW    4           // tokens per wave
#define WPB     4           // waves per block (256 threads)

__global__ __launch_bounds__(256) void TTEmbeddingLayer_84713934946739_kernel(
    const int*   __restrict__ ids,
    const float* __restrict__ core0,
    const float* __restrict__ core1,
    const float* __restrict__ core2,
    float*       __restrict__ out)
{
    __shared__ float left[TT_RANK][TT_RANK];

    const int tid  = threadIdx.x;
    const int lane = tid & 63;
    const int wave = tid >> 6;
    const int tokbase = (blockIdx.x * WPB + wave) * T_PW;   // 512 blocks * 16 tok = 8192

    // 1. ids loads — independent, issue all up front (same addr across wave -> broadcast).
    int v[T_PW];
#pragma unroll
    for (int t = 0; t < T_PW; ++t)
        v[t] = ids[tokbase + t];

    // 2. core2 segment loads — 32 independent loads per lane, scalar base + lane offset.
    int   li[T_PW];
    float x[T_PW][TT_RANK];
#pragma unroll
    for (int t = 0; t < T_PW; ++t) {
        const int vv = __builtin_amdgcn_readfirstlane(v[t]);  // wave-uniform by construction
        const int i  = vv / TT_VDIV;                          // 0..7
        li[t] = i;
        const int base = (vv - i * TT_VDIV) * TT_EMB + lane;
#pragma unroll
        for (int r = 0; r < TT_RANK; ++r)
            x[t][r] = core2[r * TT_D2 + base];
    }

    // 3. left (8x8) computed by wave 0 while waves' core2 loads are in flight.
    if (tid < TT_RANK * TT_RANK) {
        const int c  = tid & (TT_RANK - 1);
        const int ij = tid >> 3;
        const int i0 = ij >> 2;
        const int i1 = ij & 3;
        float s = 0.f;
#pragma unroll
        for (int b = 0; b < TT_RANK; ++b)
            s += core0[i0 * TT_RANK + b] * core1[(b * TT_D1 + i1) * TT_RANK + c];
        left[ij][c] = s;
    }
    __syncthreads();

    // 4. dot + coalesced store per token.
#pragma unroll
    for (int t = 0; t < T_PW; ++t) {
        float acc = 0.f;
#pragma unroll
        for (int r = 0; r < TT_RANK; ++r)
            acc += left[li[t]][r] * x[t][r];
        out[(tokbase + t) * TT_EMB + lane] = acc;
    }
}

extern "C" void kernel_launch(void* const* d_in, const int* in_sizes, int n_in,
                              void* d_out, int out_size, void* d_ws, size_t ws_size,
                              hipStream_t stream) {
    const int*   ids   = (const int*)  d_in[0];
    const float* core0 = (const float*)d_in[1];
    const float* core1 = (const float*)d_in[2];
    const float* core2 = (const float*)d_in[3];
    float*       out   = (float*)      d_out;

    const int blocks = TT_NTOK / (T_PW * WPB);  // 512
    TTEmbeddingLayer_84713934946739_kernel<<<blocks, 256, 0, stream>>>(
        ids, core0, core1, core2, out);
}